// Round 11
// baseline (413.227 us; speedup 1.0000x reference)
//
#include <hip/hip_runtime.h>
#include <hip/hip_bf16.h>

#define B_ 2
#define C_ 64
#define H_ 128
#define W_ 128
#define HS 64
#define WS 64
#define L_ 4096
#define S_ 4096
#define K1_ 576    // C*3*3
#define NCOL 1024  // C*4*4
#define SCALE_ 10.0f

typedef __attribute__((ext_vector_type(8))) short bf16x8;
typedef __attribute__((ext_vector_type(8))) _Float16 f16x8;
typedef __attribute__((ext_vector_type(4))) float f32x4;

// async global->LDS, 16B per lane (wave-uniform LDS base + lane*16).
__device__ __forceinline__ void async_copy16(const void* gsrc, void* ldst) {
    __builtin_amdgcn_global_load_lds(
        (__attribute__((address_space(1))) const void*)gsrc,
        (__attribute__((address_space(3))) void*)ldst, 16, 0, 0);
}

// transposed flat index within a 64x64 grid
__device__ __forceinline__ int TT(int x) { return ((x & 63) << 6) | (x >> 6); }

// generic 3-tap (d2) gather over Y with exact TT boundary semantics
__device__ __forceinline__ float diag3Y(const float* __restrict__ Y, int l, int s) {
    int tl = TT(l), ts = TT(s);
    float acc = 0.f;
#pragma unroll
    for (int d2 = -1; d2 <= 1; ++d2) {
        int p = tl + d2, q = ts + d2;
        if ((unsigned)p < 4096u && (unsigned)q < 4096u)
            acc += Y[((size_t)TT(p) << 12) + TT(q)];
    }
    return acc;
}

// ---------------- K0a: per-pixel channel sum-of-squares of downsampled bg ----------------
__global__ void k_sumsq(const float* __restrict__ bg, float* __restrict__ ssq) {
    int idx = blockIdx.x * 256 + threadIdx.x;  // B*64*64
    if (idx >= B_ * HS * WS) return;
    int pix = idx & 4095, b = idx >> 12;
    int i = pix >> 6, j = pix & 63;
    float ss = 0.f;
    for (int c = 0; c < C_; ++c) {
        float v = bg[((b * C_ + c) * H_ + 2 * i) * W_ + 2 * j];
        ss += v * v;
    }
    ssq[idx] = ss;
}

// ---------------- K0b: per-patch mask flag + 1/denom (3x3 box) ----------------
__global__ void k_patch_stats(const float* __restrict__ mask, const float* __restrict__ ssq,
                              float* __restrict__ denom_inv, float* __restrict__ maskedf) {
    int idx = blockIdx.x * 256 + threadIdx.x;  // B*L
    if (idx >= B_ * L_) return;
    int b = idx >> 12, l = idx & 4095, lh = l >> 6, lw = l & 63;
    float msum = 0.f, ss = 0.f;
    for (int di = -1; di <= 1; ++di)
        for (int dj = -1; dj <= 1; ++dj) {
            int i = lh + di, j = lw + dj;
            if (i >= 0 && i < HS && j >= 0 && j < WS) {
                msum += mask[(b * H_ + 2 * i) * W_ + 2 * j];
                ss += ssq[(b << 12) + (i << 6) + j];
            }
        }
    maskedf[idx] = (msum == 0.0f) ? 1.0f : 0.0f;
    denom_inv[idx] = 1.0f / fmaxf(sqrtf(ss), 0.001f);
}

// ---------------- K0c: prep v3 — LDS-staged im2col + colsT, vectorized stores -------------
// Round-11: exploit REUSE (adjacent l share the 3x3xC neighborhood) instead of per-output
// gathers. Part A (blocks 0..127): (src,lh) stages evens slab sm[c][d][j] (48KB) via
// coalesced float4 reads, then emits bgcol/fgcol rows as f16x8 from LDS. Part B (blocks
// 128..383): (c,ki) stages the 64 fixed-parity rows sm[i][x] (stride 133 to spread banks),
// emits colsT as bf16x8. Round-10's 8-wide global-gather variant regressed (+13us):
// scattered per-u gathers + 1/8 TLP; this version reads each input element once.
__global__ __launch_bounds__(256) void k_prep(const float* __restrict__ bgb,
                                              const float* __restrict__ fgb,
                                              _Float16* __restrict__ bcol,
                                              _Float16* __restrict__ fcol,
                                              __hip_bfloat16* __restrict__ colsT) {
    __shared__ float sm[12288];  // A: 64c x 3d x 64j   B: 64i x 133 (8512)
    int t = threadIdx.x;
    int bid = blockIdx.x;
    if (bid < 128) {  // ---- Part A: im2col ----
        int which = bid >> 6, lh = bid & 63;
        const float* src = which ? fgb : bgb;
        _Float16* dst = which ? fcol : bcol;
        // stage: sm[c*192 + d*64 + j] = src[c][2*(lh+d-1)][2j] or 0
#pragma unroll
        for (int it = 0; it < 24; ++it) {
            int task = it * 256 + t;       // 64*3*32 = 6144
            int c = task / 96;
            int rem = task - 96 * c;
            int d = rem >> 5, q = rem & 31;
            int iy = lh + d - 1;
            float x0 = 0.f, x1 = 0.f;
            if ((unsigned)iy < 64u) {
                float4 v = *(const float4*)&src[((size_t)c * H_ + 2 * iy) * W_ + 4 * q];
                x0 = v.x; x1 = v.z;
            }
            sm[c * 192 + d * 64 + 2 * q] = x0;
            sm[c * 192 + d * 64 + 2 * q + 1] = x1;
        }
        __syncthreads();
        // emit: 64 lw x 72 kgroups
#pragma unroll
        for (int it = 0; it < 18; ++it) {
            int task = it * 256 + t;       // 4608
            int lw = task / 72;
            int kg = task - 72 * lw;
            int k0 = kg * 8;
            f16x8 o;
#pragma unroll
            for (int u = 0; u < 8; ++u) {
                int k = k0 + u;
                int c = k / 9, r = k - 9 * c;
                int r3 = r / 3, dj = r - 3 * r3 - 1;
                int jj = lw + dj;
                float v = ((unsigned)jj < 64u) ? sm[c * 192 + r3 * 64 + jj] : 0.f;
                o[u] = (_Float16)v;
            }
            *(f16x8*)&dst[(size_t)(lh * 64 + lw) * K1_ + k0] = o;
        }
    } else {  // ---- Part B: colsT ----
        int id = bid - 128;                // 256 blocks: (c, ki)
        int c = id >> 2, ki = id & 3;
        // stage: sm[i*133 + x] = bgb[c][2i+ki-1][x] or 0
#pragma unroll
        for (int it = 0; it < 8; ++it) {
            int task = it * 256 + t;       // 64*32 = 2048
            int i = task >> 5, q = task & 31;
            int y = 2 * i + ki - 1;
            float4 v = make_float4(0.f, 0.f, 0.f, 0.f);
            if ((unsigned)y < 128u)
                v = *(const float4*)&bgb[((size_t)c * H_ + y) * W_ + 4 * q];
            int base = i * 133 + 4 * q;
            sm[base] = v.x; sm[base + 1] = v.y; sm[base + 2] = v.z; sm[base + 3] = v.w;
        }
        __syncthreads();
        // emit: 4 kj x 512 l-groups of 8
#pragma unroll
        for (int it = 0; it < 8; ++it) {
            int task = it * 256 + t;       // 2048
            int kj = task >> 9;
            int lg = task & 511;
            int l0 = lg * 8;
            int i = l0 >> 6, j0 = l0 & 63;
            bf16x8 o;
#pragma unroll
            for (int u = 0; u < 8; ++u) {
                int x = 2 * (j0 + u) + kj - 1;
                float v = ((unsigned)x < 128u) ? sm[i * 133 + x] : 0.f;
                __hip_bfloat16 r = __float2bfloat16(v);
                o[u] = *reinterpret_cast<short*>(&r);
            }
            int n = c * 16 + ki * 4 + kj;
            *(bf16x8*)&colsT[(size_t)n * L_ + l0] = o;
        }
    }
}

// ---------------- K1: scores GEMM (fp16, BK=64, XOR-8 swizzle, 2-deep pipelined) ----------
// Round-7 form (measured 399.9 total): Y materialized via single full-tile LDS epilogue +
// strip writes; diag9 fusion reverted (misaligned taps -> scalar-load storm, round-9).
__global__ __launch_bounds__(256) void k_gemm1_mfma(const _Float16* __restrict__ A,
                                                    const _Float16* __restrict__ Bm,
                                                    const float* __restrict__ dinv,
                                                    float* __restrict__ scores,
                                                    float* __restrict__ Y) {
    __shared__ __align__(16) char shraw[128 * 129 * 4];  // 66048B: 2x32KB staging / epi tile
    int t = threadIdx.x, lane = t & 63, w = t >> 6;
    int wm = w & 1, wn = w >> 1;
    int M0 = blockIdx.y * 128, N0 = blockIdx.x * 128;
    f32x4 acc[4][4] = {};

    auto stage = [&](int k0, int offh) {
        _Float16* Asb = (_Float16*)shraw + offh;
        _Float16* Bsb = Asb + 8192;
#pragma unroll
        for (int rp = 0; rp < 4; ++rp) {
            int chunk = rp * 256 + t;  // 1024 chunks of 16B
            int row = chunk >> 3;
            int kc = (chunk & 7) ^ (row & 7);  // permuted global chunk -> swizzled LDS store
            async_copy16(A + (size_t)(M0 + row) * K1_ + k0 + kc * 8, &Asb[chunk * 8]);
        }
#pragma unroll
        for (int rp = 0; rp < 4; ++rp) {
            int chunk = rp * 256 + t;
            int row = chunk >> 3;
            int kc = (chunk & 7) ^ (row & 7);
            async_copy16(Bm + (size_t)(N0 + row) * K1_ + k0 + kc * 8, &Bsb[chunk * 8]);
        }
    };

    stage(0, 0);
    int buf = 0;
    for (int k0 = 0; k0 < K1_; k0 += 64) {
        if (k0 + 64 < K1_) {
            stage(k0 + 64, (buf ^ 1) * 16384);
            asm volatile("s_waitcnt vmcnt(8)" ::: "memory");  // current tile landed
        } else {
            asm volatile("s_waitcnt vmcnt(0)" ::: "memory");
        }
        __builtin_amdgcn_s_barrier();
        _Float16* As = (_Float16*)shraw + buf * 16384;
        _Float16* Bs = As + 8192;
        int qc = lane >> 4, mr = lane & 15;
#pragma unroll
        for (int kk = 0; kk < 2; ++kk) {
            int c = kk * 4 + qc;
            f16x8 af[4], bfr[4];
#pragma unroll
            for (int i = 0; i < 4; ++i) {
                int ra = wm * 64 + i * 16 + mr;
                int rb = wn * 64 + i * 16 + mr;
                af[i] = *(const f16x8*)&As[ra * 64 + (c ^ (ra & 7)) * 8];
                bfr[i] = *(const f16x8*)&Bs[rb * 64 + (c ^ (rb & 7)) * 8];
            }
#pragma unroll
            for (int mt = 0; mt < 4; ++mt)
#pragma unroll
                for (int nt = 0; nt < 4; ++nt)
                    acc[mt][nt] = __builtin_amdgcn_mfma_f32_16x16x32_f16(af[mt], bfr[nt], acc[mt][nt], 0, 0, 0);
        }
        __builtin_amdgcn_s_barrier();  // readers done before next iter overwrites buf^1
        buf ^= 1;
    }
    int col = lane & 15, rq = (lane >> 4) * 4;
    // strip writes: raw scores on rows/cols {0,1,126,127} of this tile
#pragma unroll
    for (int mt = 0; mt < 4; ++mt)
#pragma unroll
        for (int r = 0; r < 4; ++r) {
            int ml = wm * 64 + mt * 16 + rq + r;
            bool rstrip = (ml <= 1) || (ml >= 126);
            float dv = dinv[M0 + ml];
#pragma unroll
            for (int nt = 0; nt < 4; ++nt) {
                int nl = wn * 64 + nt * 16 + col;
                bool cstrip = (nl <= 1) || (nl >= 126);
                if (rstrip || cstrip)
                    scores[((size_t)(M0 + ml) << 12) + N0 + nl] = acc[mt][nt][r] * dv;
            }
        }
    // Y interior via single full-tile LDS pass (128x129 f32)
    float* sm = (float*)shraw;
#pragma unroll
    for (int mt = 0; mt < 4; ++mt)
#pragma unroll
        for (int r = 0; r < 4; ++r) {
            int ml = wm * 64 + mt * 16 + rq + r;
            float dv = dinv[M0 + ml];
#pragma unroll
            for (int nt = 0; nt < 4; ++nt) {
                int nl = wn * 64 + nt * 16 + col;
                sm[ml * 129 + nl] = acc[mt][nt][r] * dv;
            }
        }
    __syncthreads();
    for (int e = t; e < 126 * 128; e += 256) {
        int rr = 1 + (e >> 7);
        int cc = e & 127;
        if (cc < 1 || cc > 126) continue;
        float y = sm[(rr - 1) * 129 + cc - 1] + sm[rr * 129 + cc] + sm[(rr + 1) * 129 + cc + 1];
        Y[((size_t)(M0 + rr) << 12) + N0 + cc] = y;
    }
}

// ---------------- K2a: Y boundary rows/cols from score strips (exact flat bounds) ---------
__global__ void k_pass1_edge(const float* __restrict__ scores, float* __restrict__ Y) {
    int idx = blockIdx.x * 256 + threadIdx.x;  // 2*64*4096
    int a, c;
    if (idx < 262144) {
        int ri = idx >> 12;  // 0..63
        a = (ri >> 1) * 128 + ((ri & 1) ? 127 : 0);
        c = idx & 4095;
    } else {
        int j = idx - 262144;
        int ci = j >> 12;
        c = (ci >> 1) * 128 + ((ci & 1) ? 127 : 0);
        a = j & 4095;
    }
    float acc = 0.f;
#pragma unroll
    for (int d = -1; d <= 1; ++d) {
        int aa = a + d, cc = c + d;
        if ((unsigned)aa < 4096u && (unsigned)cc < 4096u)
            acc += scores[((size_t)aa << 12) + cc];
    }
    Y[((size_t)a << 12) + c] = acc;
}

// ---------------- K2b: pass2 — 3-tap (rows +-64) + local-max exp + transpose -> softT -----
// Round-7 form: 12 ALIGNED float4 taps register-prefetched (alignment is why this beats
// the fused 9-tap variant: misaligned taps lower to 4x scalar loads — round-9 ERRATA).
__global__ __launch_bounds__(256) void k_soft3(const float* __restrict__ Y,
                                               const float* __restrict__ maskedf,
                                               __hip_bfloat16* __restrict__ softT,
                                               float* __restrict__ pml, float* __restrict__ pz) {
    __shared__ float tile[64][65];
    __shared__ float red[16][64];
    __shared__ float mloc[64];
    int t = threadIdx.x;
    int sx4 = t & 15, lg = t >> 4;
    int bid = blockIdx.x;
    int swz = (bid & 7) * 512 + (bid >> 3);
    int dg = swz >> 6, pos = swz & 63;
    int by = pos, bx = (pos + dg) & 63;
    int s0 = bx * 64, l0 = by * 64;
    bool interior = (bx >= 1) && (bx <= 62) && (by >= 1) && (by <= 62);
    float p0 = -3.0e38f, p1 = -3.0e38f, p2 = -3.0e38f, p3 = -3.0e38f;
    if (interior) {
        float4 v[12];
        float mk[4];
#pragma unroll
        for (int j = 0; j < 4; ++j) {
            int lloc = lg + 16 * j;
#pragma unroll
            for (int d2 = 0; d2 < 3; ++d2) {
                const float* p = Y + ((size_t)(64 * (by + d2 - 1) + lloc) << 12) + 64 * (bx + d2 - 1) + 4 * sx4;
                v[j * 3 + d2] = *(const float4*)p;
            }
        }
#pragma unroll
        for (int j = 0; j < 4; ++j) mk[j] = maskedf[l0 + lg + 16 * j];
#pragma unroll
        for (int j = 0; j < 4; ++j) {
            int lloc = lg + 16 * j;
            float a0 = v[j * 3].x + v[j * 3 + 1].x + v[j * 3 + 2].x;
            float a1 = v[j * 3].y + v[j * 3 + 1].y + v[j * 3 + 2].y;
            float a2 = v[j * 3].z + v[j * 3 + 1].z + v[j * 3 + 2].z;
            float a3 = v[j * 3].w + v[j * 3 + 1].w + v[j * 3 + 2].w;
            if (mk[j] != 0.f) { a0 = -1000.f; a1 = -1000.f; a2 = -1000.f; a3 = -1000.f; }
            tile[lloc][4 * sx4 + 0] = a0;
            tile[lloc][4 * sx4 + 1] = a1;
            tile[lloc][4 * sx4 + 2] = a2;
            tile[lloc][4 * sx4 + 3] = a3;
            p0 = fmaxf(p0, a0); p1 = fmaxf(p1, a1); p2 = fmaxf(p2, a2); p3 = fmaxf(p3, a3);
        }
    } else {
#pragma unroll
        for (int j = 0; j < 4; ++j) {
            int lloc = lg + 16 * j;
            int l = l0 + lloc;
            bool mk = (maskedf[l] != 0.f);
            float a0 = mk ? -1000.f : diag3Y(Y, l, s0 + 4 * sx4 + 0);
            float a1 = mk ? -1000.f : diag3Y(Y, l, s0 + 4 * sx4 + 1);
            float a2 = mk ? -1000.f : diag3Y(Y, l, s0 + 4 * sx4 + 2);
            float a3 = mk ? -1000.f : diag3Y(Y, l, s0 + 4 * sx4 + 3);
            tile[lloc][4 * sx4 + 0] = a0;
            tile[lloc][4 * sx4 + 1] = a1;
            tile[lloc][4 * sx4 + 2] = a2;
            tile[lloc][4 * sx4 + 3] = a3;
            p0 = fmaxf(p0, a0); p1 = fmaxf(p1, a1); p2 = fmaxf(p2, a2); p3 = fmaxf(p3, a3);
        }
    }
    red[lg][4 * sx4 + 0] = p0;
    red[lg][4 * sx4 + 1] = p1;
    red[lg][4 * sx4 + 2] = p2;
    red[lg][4 * sx4 + 3] = p3;
    __syncthreads();
    if (t < 64) {
        float m = -3.0e38f;
#pragma unroll
        for (int g = 0; g < 16; ++g) m = fmaxf(m, red[g][t]);
        mloc[t] = m;
        pml[(size_t)(s0 + t) * 64 + by] = m;
    }
    __syncthreads();
    float m0 = mloc[4 * sx4 + 0], m1 = mloc[4 * sx4 + 1], m2 = mloc[4 * sx4 + 2], m3 = mloc[4 * sx4 + 3];
    float z0 = 0.f, z1 = 0.f, z2 = 0.f, z3 = 0.f;
#pragma unroll
    for (int j = 0; j < 4; ++j) {
        int lloc = lg + 16 * j;
        float e0 = __expf(SCALE_ * (tile[lloc][4 * sx4 + 0] - m0));
        float e1 = __expf(SCALE_ * (tile[lloc][4 * sx4 + 1] - m1));
        float e2 = __expf(SCALE_ * (tile[lloc][4 * sx4 + 2] - m2));
        float e3 = __expf(SCALE_ * (tile[lloc][4 * sx4 + 3] - m3));
        tile[lloc][4 * sx4 + 0] = e0;
        tile[lloc][4 * sx4 + 1] = e1;
        tile[lloc][4 * sx4 + 2] = e2;
        tile[lloc][4 * sx4 + 3] = e3;
        z0 += e0; z1 += e1; z2 += e2; z3 += e3;
    }
    red[lg][4 * sx4 + 0] = z0;
    red[lg][4 * sx4 + 1] = z1;
    red[lg][4 * sx4 + 2] = z2;
    red[lg][4 * sx4 + 3] = z3;
    __syncthreads();
    if (t < 64) {
        float zz = 0.f;
#pragma unroll
        for (int g = 0; g < 16; ++g) zz += red[g][t];
        pz[(size_t)(s0 + t) * 64 + by] = zz;
    }
#pragma unroll
    for (int pp = 0; pp < 2; ++pp) {
        int chunk = pp * 256 + t;
        int sloc = chunk >> 3, lb = (chunk & 7) * 8;
        bf16x8 o;
#pragma unroll
        for (int k = 0; k < 8; ++k) {
            __hip_bfloat16 r = __float2bfloat16(tile[lb + k][sloc]);
            o[k] = *reinterpret_cast<short*>(&r);
        }
        *(bf16x8*)(softT + ((size_t)(s0 + sloc) << 12) + l0 + lb) = o;
    }
}

// ---------------- K3: fused zfix+rescale: block per s-row --------------------------------
__global__ __launch_bounds__(256) void k_zr(const float* __restrict__ pml,
                                            const float* __restrict__ pz,
                                            __hip_bfloat16* __restrict__ softT) {
    __shared__ float facs[64];
    int t = threadIdx.x;
    int s = blockIdx.x;
    if (t < 64) {
        float pmv = pml[(size_t)s * 64 + t];
        float m = pmv;
#pragma unroll
        for (int off = 1; off < 64; off <<= 1) m = fmaxf(m, __shfl_xor(m, off));
        float fc = __expf(SCALE_ * (pmv - m));
        float g = pz[(size_t)s * 64 + t] * fc;
#pragma unroll
        for (int off = 1; off < 64; off <<= 1) g += __shfl_xor(g, off);
        facs[t] = fc * (1.0f / g);
    }
    __syncthreads();
    size_t rowbase = (size_t)s << 12;
#pragma unroll
    for (int p = 0; p < 2; ++p) {
        int chunk = t + p * 256;
        float f = facs[chunk >> 3];
        bf16x8 v = *(const bf16x8*)(softT + rowbase + chunk * 8);
        bf16x8 o;
#pragma unroll
        for (int k = 0; k < 8; ++k) {
            unsigned short us = (unsigned short)v[k];
            float x = __uint_as_float((unsigned)us << 16) * f;
            __hip_bfloat16 r = __float2bfloat16(x);
            o[k] = *reinterpret_cast<short*>(&r);
        }
        *(bf16x8*)(softT + rowbase + chunk * 8) = o;
    }
}

// ---------------- K6: deconv GEMM, split-K z=2, BM=128 BN=128 BK=64, 2-deep pipelined -----
// n-major epilogue (round-7) + counted-vmcnt dbuf pipeline (round-6).
__global__ __launch_bounds__(256) void k_gemm2_mfma(const __hip_bfloat16* __restrict__ softT,
                                                    const __hip_bfloat16* __restrict__ colsT,
                                                    float* __restrict__ patchP) {
    __shared__ __hip_bfloat16 AsB[2][16384];  // per buf: A 128x64 (8192) + B 128x64 (8192)
    int t = threadIdx.x, lane = t & 63, w = t >> 6;
    int wm = w & 1, wn = w >> 1;
    int flat = blockIdx.x + (blockIdx.y << 3) + (blockIdx.z << 8);  // grid (8,32,2) = 512
    int swz = (flat & 7) * 64 + (flat >> 3);  // XCD k -> contiguous 64-block chunk
    int zp = swz >> 8;
    int rem = swz & 255;
    int yp = rem >> 3, xp = rem & 7;
    int M0 = yp * 128, N0 = xp * 128;
    int kbase = zp * 2048;
    f32x4 acc[4][4] = {};

    auto stage = [&](int k0, int bsel) {
        __hip_bfloat16* Asb = AsB[bsel];
        __hip_bfloat16* Bsb = Asb + 8192;
#pragma unroll
        for (int rp = 0; rp < 4; ++rp) {
            int chunk = rp * 256 + t;
            int row = chunk >> 3;
            int kc = (chunk & 7) ^ (row & 7);
            async_copy16(softT + ((size_t)(M0 + row) << 12) + k0 + kc * 8, &Asb[chunk * 8]);
        }
#pragma unroll
        for (int rp = 0; rp < 4; ++rp) {
            int chunk = rp * 256 + t;
            int row = chunk >> 3;
            int kc = (chunk & 7) ^ (row & 7);
            async_copy16(colsT + ((size_t)(N0 + row) << 12) + k0 + kc * 8, &Bsb[chunk * 8]);
        }
    };

    stage(kbase, 0);
    int buf = 0;
    for (int k0 = kbase; k0 < kbase + 2048; k0 += 64) {
        if (k0 + 64 < kbase + 2048) {
            stage(k0 + 64, buf ^ 1);
            asm volatile("s_waitcnt vmcnt(8)" ::: "memory");  // current tile's 8 landed
        } else {
            asm volatile("s_waitcnt vmcnt(0)" ::: "memory");
        }
        __builtin_amdgcn_s_barrier();
        __hip_bfloat16* As = AsB[buf];
        __hip_bfloat16* Bs = As + 8192;
        int qc = lane >> 4, mr = lane & 15;
#pragma unroll
        for (int kk = 0; kk < 2; ++kk) {
            int c = kk * 4 + qc;
            bf16x8 af[4], bfr[4];
#pragma unroll
            for (int i = 0; i < 4; ++i) {
                int rowa = wm * 64 + i * 16 + mr;
                af[i] = *(const bf16x8*)&As[rowa * 64 + (c ^ (rowa & 7)) * 8];
                int rowb = wn * 64 + i * 16 + mr;
                bfr[i] = *(const bf16x8*)&Bs[rowb * 64 + (c ^ (rowb & 7)) * 8];
            }
#pragma unroll
            for (int mt = 0; mt < 4; ++mt)
#pragma unroll
                for (int nt = 0; nt < 4; ++nt)
                    acc[mt][nt] = __builtin_amdgcn_mfma_f32_16x16x32_bf16(af[mt], bfr[nt], acc[mt][nt], 0, 0, 0);
        }
        __builtin_amdgcn_s_barrier();  // readers done before next iter overwrites buf^1
        buf ^= 1;
    }
    // n-major epilogue: P[n*4096 + m], 16B-aligned float4 per (mt,nt) (r -> m0+0..3)
    float* P = patchP + ((size_t)zp << 22);
    int col = lane & 15, rq = (lane >> 4) * 4;
#pragma unroll
    for (int mt = 0; mt < 4; ++mt) {
        int m0 = M0 + wm * 64 + mt * 16 + rq;
#pragma unroll
        for (int nt = 0; nt < 4; ++nt) {
            int n = N0 + wn * 64 + nt * 16 + col;
            *(f32x4*)&P[(size_t)n * 4096 + m0] = acc[mt][nt];
        }
    }
}

// ---------------- K7: overlap-add gather over both K-partials, n-major patchP -------------
__global__ void k_col2im(const float* __restrict__ patchP, float* __restrict__ outb) {
    int idx = blockIdx.x * 256 + threadIdx.x;  // C*H*W
    if (idx >= C_ * H_ * W_) return;
    int x = idx & 127, y = (idx >> 7) & 127, c = idx >> 14;
    const float* P0 = patchP;
    const float* P1 = patchP + (1u << 22);
    float acc = 0.f;
    int ki0 = (y + 1) & 1, kj0 = (x + 1) & 1;
#pragma unroll
    for (int ki = ki0; ki < 4; ki += 2) {
        int i = (y + 1 - ki) >> 1;
        if (i < 0 || i >= HS) continue;
#pragma unroll
        for (int kj = kj0; kj < 4; kj += 2) {
            int j = (x + 1 - kj) >> 1;
            if (j < 0 || j >= WS) continue;
            size_t off = ((size_t)(c * 16 + ki * 4 + kj) << 12) + i * 64 + j;
            acc += P0[off] + P1[off];
        }
    }
    outb[idx] = acc;
}

extern "C" void kernel_launch(void* const* d_in, const int* in_sizes, int n_in,
                              void* d_out, int out_size, void* d_ws, size_t ws_size,
                              hipStream_t stream) {
    (void)in_sizes; (void)n_in; (void)out_size; (void)ws_size;
    const float* fg = (const float*)d_in[0];
    const float* bg = (const float*)d_in[1];
    const float* mask = (const float*)d_in[2];
    float* out = (float*)d_out;

    // ---- workspace (float offsets) ----
    float* ws = (float*)d_ws;
    float* scores = ws;                                          // strip-only scores
    float* patchP = ws;                                          // alias: 2 x 4,194,304 f
    float* Y = ws + 16777216;                                    // 16,777,216 f
    _Float16* bgcol = (_Float16*)(ws + 33554432);                // 2,359,296 f16
    _Float16* fgcol = (_Float16*)(ws + 34734080);
    __hip_bfloat16* softT = (__hip_bfloat16*)(ws + 38273024);    // 16,777,216 bf16
    __hip_bfloat16* colsT = (__hip_bfloat16*)(ws + 46661632);    // 4,194,304 bf16
    float* pml = ws + 48758784;        // 262,144
    float* pz = ws + 49020928;         // 262,144
    float* denom_inv = ws + 49283072;  // 8,192 (B*L)
    float* maskedf = ws + 49291264;    // 8,192
    float* ssq = ws + 49299456;        // 8,192

    k_sumsq<<<(B_ * HS * WS) / 256, 256, 0, stream>>>(bg, ssq);
    k_patch_stats<<<(B_ * L_) / 256, 256, 0, stream>>>(mask, ssq, denom_inv, maskedf);

    for (int b = 0; b < B_; ++b) {
        const float* bgb = bg + (size_t)b * C_ * H_ * W_;
        const float* fgb = fg + (size_t)b * C_ * H_ * W_;

        k_prep<<<384, 256, 0, stream>>>(bgb, fgb, bgcol, fgcol, colsT);

        dim3 g1(32, 32);
        k_gemm1_mfma<<<g1, 256, 0, stream>>>(bgcol, fgcol, denom_inv + b * L_, scores, Y);
        k_pass1_edge<<<2048, 256, 0, stream>>>(scores, Y);

        k_soft3<<<4096, 256, 0, stream>>>(Y, maskedf + b * L_, softT, pml, pz);
        k_zr<<<4096, 256, 0, stream>>>(pml, pz, softT);

        dim3 g5(8, 32, 2);
        k_gemm2_mfma<<<g5, 256, 0, stream>>>(softT, colsT, patchP);
        k_col2im<<<(C_ * H_ * W_) / 256, 256, 0, stream>>>(patchP, out + (size_t)b * C_ * H_ * W_);
    }
}

// Round 12
// 387.012 us; speedup vs baseline: 1.0677x; 1.0677x over previous
//
#include <hip/hip_runtime.h>
#include <hip/hip_bf16.h>

#define B_ 2
#define C_ 64
#define H_ 128
#define W_ 128
#define HS 64
#define WS 64
#define L_ 4096
#define S_ 4096
#define K1_ 576    // C*3*3
#define NCOL 1024  // C*4*4
#define SCALE_ 10.0f

typedef __attribute__((ext_vector_type(8))) short bf16x8;
typedef __attribute__((ext_vector_type(8))) _Float16 f16x8;
typedef __attribute__((ext_vector_type(4))) float f32x4;

// async global->LDS, 16B per lane (wave-uniform LDS base + lane*16).
__device__ __forceinline__ void async_copy16(const void* gsrc, void* ldst) {
    __builtin_amdgcn_global_load_lds(
        (__attribute__((address_space(1))) const void*)gsrc,
        (__attribute__((address_space(3))) void*)ldst, 16, 0, 0);
}

// transposed flat index within a 64x64 grid
__device__ __forceinline__ int TT(int x) { return ((x & 63) << 6) | (x >> 6); }

// generic 3-tap (d2) gather over Y with exact TT boundary semantics
__device__ __forceinline__ float diag3Y(const float* __restrict__ Y, int l, int s) {
    int tl = TT(l), ts = TT(s);
    float acc = 0.f;
#pragma unroll
    for (int d2 = -1; d2 <= 1; ++d2) {
        int p = tl + d2, q = ts + d2;
        if ((unsigned)p < 4096u && (unsigned)q < 4096u)
            acc += Y[((size_t)TT(p) << 12) + TT(q)];
    }
    return acc;
}

// ---------------- K0a: per-pixel channel sum-of-squares of downsampled bg ----------------
__global__ void k_sumsq(const float* __restrict__ bg, float* __restrict__ ssq) {
    int idx = blockIdx.x * 256 + threadIdx.x;  // B*64*64
    if (idx >= B_ * HS * WS) return;
    int pix = idx & 4095, b = idx >> 12;
    int i = pix >> 6, j = pix & 63;
    float ss = 0.f;
    for (int c = 0; c < C_; ++c) {
        float v = bg[((b * C_ + c) * H_ + 2 * i) * W_ + 2 * j];
        ss += v * v;
    }
    ssq[idx] = ss;
}

// ---------------- K0b: per-patch mask flag + 1/denom (3x3 box) ----------------
__global__ void k_patch_stats(const float* __restrict__ mask, const float* __restrict__ ssq,
                              float* __restrict__ denom_inv, float* __restrict__ maskedf) {
    int idx = blockIdx.x * 256 + threadIdx.x;  // B*L
    if (idx >= B_ * L_) return;
    int b = idx >> 12, l = idx & 4095, lh = l >> 6, lw = l & 63;
    float msum = 0.f, ss = 0.f;
    for (int di = -1; di <= 1; ++di)
        for (int dj = -1; dj <= 1; ++dj) {
            int i = lh + di, j = lw + dj;
            if (i >= 0 && i < HS && j >= 0 && j < WS) {
                msum += mask[(b * H_ + 2 * i) * W_ + 2 * j];
                ss += ssq[(b << 12) + (i << 6) + j];
            }
        }
    maskedf[idx] = (msum == 0.0f) ? 1.0f : 0.0f;
    denom_inv[idx] = 1.0f / fmaxf(sqrtf(ss), 0.001f);
}

// ---------------- K0c: fused prep (R7 scalar form; colsT now f16) -------------------------
__global__ void k_prep(const float* __restrict__ bgb, const float* __restrict__ fgb,
                       _Float16* __restrict__ bcol, _Float16* __restrict__ fcol,
                       _Float16* __restrict__ colsT) {
    int idx = blockIdx.x * 256 + threadIdx.x;
    if (idx < 2 * L_ * K1_) {  // im2col part (block-uniform split)
        int which = idx >= L_ * K1_;
        int id = which ? idx - L_ * K1_ : idx;
        const float* src = which ? fgb : bgb;
        _Float16* dst = which ? fcol : bcol;
        int k = id % K1_;
        int l = id / K1_;
        int c = k / 9, r = k - 9 * c;
        int r3 = r / 3;
        int di = r3 - 1, dj = r - 3 * r3 - 1;
        int i = (l >> 6) + di, j = (l & 63) + dj;
        float v = 0.f;
        if (i >= 0 && i < HS && j >= 0 && j < WS) v = src[(c * H_ + 2 * i) * W_ + 2 * j];
        dst[id] = (_Float16)v;
    } else {  // colsT part
        int id = idx - 2 * L_ * K1_;  // NCOL*L, l fastest
        int l = id & 4095, n = id >> 12;
        int kj = n & 3, ki = (n >> 2) & 3, c = n >> 4;
        int y = 2 * (l >> 6) + ki - 1, x = 2 * (l & 63) + kj - 1;
        float v = 0.f;
        if (y >= 0 && y < H_ && x >= 0 && x < W_) v = bgb[(c * H_ + y) * W_ + x];
        colsT[id] = (_Float16)v;
    }
}

// ---------------- K1: scores GEMM (fp16, BK=64, XOR-8 swizzle, 2-deep pipelined) ----------
// Round-7 form (best measured): Y materialized via single full-tile LDS epilogue + strips.
__global__ __launch_bounds__(256) void k_gemm1_mfma(const _Float16* __restrict__ A,
                                                    const _Float16* __restrict__ Bm,
                                                    const float* __restrict__ dinv,
                                                    float* __restrict__ scores,
                                                    float* __restrict__ Y) {
    __shared__ __align__(16) char shraw[128 * 129 * 4];  // 66048B: 2x32KB staging / epi tile
    int t = threadIdx.x, lane = t & 63, w = t >> 6;
    int wm = w & 1, wn = w >> 1;
    int M0 = blockIdx.y * 128, N0 = blockIdx.x * 128;
    f32x4 acc[4][4] = {};

    auto stage = [&](int k0, int offh) {
        _Float16* Asb = (_Float16*)shraw + offh;
        _Float16* Bsb = Asb + 8192;
#pragma unroll
        for (int rp = 0; rp < 4; ++rp) {
            int chunk = rp * 256 + t;  // 1024 chunks of 16B
            int row = chunk >> 3;
            int kc = (chunk & 7) ^ (row & 7);  // permuted global chunk -> swizzled LDS store
            async_copy16(A + (size_t)(M0 + row) * K1_ + k0 + kc * 8, &Asb[chunk * 8]);
        }
#pragma unroll
        for (int rp = 0; rp < 4; ++rp) {
            int chunk = rp * 256 + t;
            int row = chunk >> 3;
            int kc = (chunk & 7) ^ (row & 7);
            async_copy16(Bm + (size_t)(N0 + row) * K1_ + k0 + kc * 8, &Bsb[chunk * 8]);
        }
    };

    stage(0, 0);
    int buf = 0;
    for (int k0 = 0; k0 < K1_; k0 += 64) {
        if (k0 + 64 < K1_) {
            stage(k0 + 64, (buf ^ 1) * 16384);
            asm volatile("s_waitcnt vmcnt(8)" ::: "memory");  // current tile landed
        } else {
            asm volatile("s_waitcnt vmcnt(0)" ::: "memory");
        }
        __builtin_amdgcn_s_barrier();
        _Float16* As = (_Float16*)shraw + buf * 16384;
        _Float16* Bs = As + 8192;
        int qc = lane >> 4, mr = lane & 15;
#pragma unroll
        for (int kk = 0; kk < 2; ++kk) {
            int c = kk * 4 + qc;
            f16x8 af[4], bfr[4];
#pragma unroll
            for (int i = 0; i < 4; ++i) {
                int ra = wm * 64 + i * 16 + mr;
                int rb = wn * 64 + i * 16 + mr;
                af[i] = *(const f16x8*)&As[ra * 64 + (c ^ (ra & 7)) * 8];
                bfr[i] = *(const f16x8*)&Bs[rb * 64 + (c ^ (rb & 7)) * 8];
            }
#pragma unroll
            for (int mt = 0; mt < 4; ++mt)
#pragma unroll
                for (int nt = 0; nt < 4; ++nt)
                    acc[mt][nt] = __builtin_amdgcn_mfma_f32_16x16x32_f16(af[mt], bfr[nt], acc[mt][nt], 0, 0, 0);
        }
        __builtin_amdgcn_s_barrier();  // readers done before next iter overwrites buf^1
        buf ^= 1;
    }
    int col = lane & 15, rq = (lane >> 4) * 4;
    // strip writes: raw scores on rows/cols {0,1,126,127} of this tile
#pragma unroll
    for (int mt = 0; mt < 4; ++mt)
#pragma unroll
        for (int r = 0; r < 4; ++r) {
            int ml = wm * 64 + mt * 16 + rq + r;
            bool rstrip = (ml <= 1) || (ml >= 126);
            float dv = dinv[M0 + ml];
#pragma unroll
            for (int nt = 0; nt < 4; ++nt) {
                int nl = wn * 64 + nt * 16 + col;
                bool cstrip = (nl <= 1) || (nl >= 126);
                if (rstrip || cstrip)
                    scores[((size_t)(M0 + ml) << 12) + N0 + nl] = acc[mt][nt][r] * dv;
            }
        }
    // Y interior via single full-tile LDS pass (128x129 f32)
    float* sm = (float*)shraw;
#pragma unroll
    for (int mt = 0; mt < 4; ++mt)
#pragma unroll
        for (int r = 0; r < 4; ++r) {
            int ml = wm * 64 + mt * 16 + rq + r;
            float dv = dinv[M0 + ml];
#pragma unroll
            for (int nt = 0; nt < 4; ++nt) {
                int nl = wn * 64 + nt * 16 + col;
                sm[ml * 129 + nl] = acc[mt][nt][r] * dv;
            }
        }
    __syncthreads();
    for (int e = t; e < 126 * 128; e += 256) {
        int rr = 1 + (e >> 7);
        int cc = e & 127;
        if (cc < 1 || cc > 126) continue;
        float y = sm[(rr - 1) * 129 + cc - 1] + sm[rr * 129 + cc] + sm[(rr + 1) * 129 + cc + 1];
        Y[((size_t)(M0 + rr) << 12) + N0 + cc] = y;
    }
}

// ---------------- K2a: Y boundary rows/cols from score strips (exact flat bounds) ---------
__global__ void k_pass1_edge(const float* __restrict__ scores, float* __restrict__ Y) {
    int idx = blockIdx.x * 256 + threadIdx.x;  // 2*64*4096
    int a, c;
    if (idx < 262144) {
        int ri = idx >> 12;  // 0..63
        a = (ri >> 1) * 128 + ((ri & 1) ? 127 : 0);
        c = idx & 4095;
    } else {
        int j = idx - 262144;
        int ci = j >> 12;
        c = (ci >> 1) * 128 + ((ci & 1) ? 127 : 0);
        a = j & 4095;
    }
    float acc = 0.f;
#pragma unroll
    for (int d = -1; d <= 1; ++d) {
        int aa = a + d, cc = c + d;
        if ((unsigned)aa < 4096u && (unsigned)cc < 4096u)
            acc += scores[((size_t)aa << 12) + cc];
    }
    Y[((size_t)a << 12) + c] = acc;
}

// ---------------- K2b: pass2 — 3-tap + local-max exp + transpose -> softT (f16) -----------
__global__ __launch_bounds__(256) void k_soft3(const float* __restrict__ Y,
                                               const float* __restrict__ maskedf,
                                               _Float16* __restrict__ softT,
                                               float* __restrict__ pml, float* __restrict__ pz) {
    __shared__ float tile[64][65];
    __shared__ float red[16][64];
    __shared__ float mloc[64];
    int t = threadIdx.x;
    int sx4 = t & 15, lg = t >> 4;
    int bid = blockIdx.x;
    int swz = (bid & 7) * 512 + (bid >> 3);
    int dg = swz >> 6, pos = swz & 63;
    int by = pos, bx = (pos + dg) & 63;
    int s0 = bx * 64, l0 = by * 64;
    bool interior = (bx >= 1) && (bx <= 62) && (by >= 1) && (by <= 62);
    float p0 = -3.0e38f, p1 = -3.0e38f, p2 = -3.0e38f, p3 = -3.0e38f;
    if (interior) {
        float4 v[12];
        float mk[4];
#pragma unroll
        for (int j = 0; j < 4; ++j) {
            int lloc = lg + 16 * j;
#pragma unroll
            for (int d2 = 0; d2 < 3; ++d2) {
                const float* p = Y + ((size_t)(64 * (by + d2 - 1) + lloc) << 12) + 64 * (bx + d2 - 1) + 4 * sx4;
                v[j * 3 + d2] = *(const float4*)p;
            }
        }
#pragma unroll
        for (int j = 0; j < 4; ++j) mk[j] = maskedf[l0 + lg + 16 * j];
#pragma unroll
        for (int j = 0; j < 4; ++j) {
            int lloc = lg + 16 * j;
            float a0 = v[j * 3].x + v[j * 3 + 1].x + v[j * 3 + 2].x;
            float a1 = v[j * 3].y + v[j * 3 + 1].y + v[j * 3 + 2].y;
            float a2 = v[j * 3].z + v[j * 3 + 1].z + v[j * 3 + 2].z;
            float a3 = v[j * 3].w + v[j * 3 + 1].w + v[j * 3 + 2].w;
            if (mk[j] != 0.f) { a0 = -1000.f; a1 = -1000.f; a2 = -1000.f; a3 = -1000.f; }
            tile[lloc][4 * sx4 + 0] = a0;
            tile[lloc][4 * sx4 + 1] = a1;
            tile[lloc][4 * sx4 + 2] = a2;
            tile[lloc][4 * sx4 + 3] = a3;
            p0 = fmaxf(p0, a0); p1 = fmaxf(p1, a1); p2 = fmaxf(p2, a2); p3 = fmaxf(p3, a3);
        }
    } else {
#pragma unroll
        for (int j = 0; j < 4; ++j) {
            int lloc = lg + 16 * j;
            int l = l0 + lloc;
            bool mk = (maskedf[l] != 0.f);
            float a0 = mk ? -1000.f : diag3Y(Y, l, s0 + 4 * sx4 + 0);
            float a1 = mk ? -1000.f : diag3Y(Y, l, s0 + 4 * sx4 + 1);
            float a2 = mk ? -1000.f : diag3Y(Y, l, s0 + 4 * sx4 + 2);
            float a3 = mk ? -1000.f : diag3Y(Y, l, s0 + 4 * sx4 + 3);
            tile[lloc][4 * sx4 + 0] = a0;
            tile[lloc][4 * sx4 + 1] = a1;
            tile[lloc][4 * sx4 + 2] = a2;
            tile[lloc][4 * sx4 + 3] = a3;
            p0 = fmaxf(p0, a0); p1 = fmaxf(p1, a1); p2 = fmaxf(p2, a2); p3 = fmaxf(p3, a3);
        }
    }
    red[lg][4 * sx4 + 0] = p0;
    red[lg][4 * sx4 + 1] = p1;
    red[lg][4 * sx4 + 2] = p2;
    red[lg][4 * sx4 + 3] = p3;
    __syncthreads();
    if (t < 64) {
        float m = -3.0e38f;
#pragma unroll
        for (int g = 0; g < 16; ++g) m = fmaxf(m, red[g][t]);
        mloc[t] = m;
        pml[(size_t)(s0 + t) * 64 + by] = m;
    }
    __syncthreads();
    float m0 = mloc[4 * sx4 + 0], m1 = mloc[4 * sx4 + 1], m2 = mloc[4 * sx4 + 2], m3 = mloc[4 * sx4 + 3];
    float z0 = 0.f, z1 = 0.f, z2 = 0.f, z3 = 0.f;
#pragma unroll
    for (int j = 0; j < 4; ++j) {
        int lloc = lg + 16 * j;
        float e0 = __expf(SCALE_ * (tile[lloc][4 * sx4 + 0] - m0));
        float e1 = __expf(SCALE_ * (tile[lloc][4 * sx4 + 1] - m1));
        float e2 = __expf(SCALE_ * (tile[lloc][4 * sx4 + 2] - m2));
        float e3 = __expf(SCALE_ * (tile[lloc][4 * sx4 + 3] - m3));
        tile[lloc][4 * sx4 + 0] = e0;
        tile[lloc][4 * sx4 + 1] = e1;
        tile[lloc][4 * sx4 + 2] = e2;
        tile[lloc][4 * sx4 + 3] = e3;
        z0 += e0; z1 += e1; z2 += e2; z3 += e3;
    }
    red[lg][4 * sx4 + 0] = z0;
    red[lg][4 * sx4 + 1] = z1;
    red[lg][4 * sx4 + 2] = z2;
    red[lg][4 * sx4 + 3] = z3;
    __syncthreads();
    if (t < 64) {
        float zz = 0.f;
#pragma unroll
        for (int g = 0; g < 16; ++g) zz += red[g][t];
        pz[(size_t)(s0 + t) * 64 + by] = zz;
    }
#pragma unroll
    for (int pp = 0; pp < 2; ++pp) {
        int chunk = pp * 256 + t;
        int sloc = chunk >> 3, lb = (chunk & 7) * 8;
        f16x8 o;
#pragma unroll
        for (int k = 0; k < 8; ++k) o[k] = (_Float16)tile[lb + k][sloc];
        *(f16x8*)(softT + ((size_t)(s0 + sloc) << 12) + l0 + lb) = o;
    }
}

// ---------------- K3: facs = fc/g computed IN-PLACE into pml (replaces k_zr) --------------
// f(s,lb) = exp(SCALE*(pml[s][lb]-max_lb)) / sum_lb(pz*fc). Applied inside gemm2's
// fragment path (constant per A-row per K-step since one K-step = one l-block).
__global__ __launch_bounds__(256) void k_facs(float* __restrict__ pml,
                                              const float* __restrict__ pz) {
    int t = threadIdx.x & 63;
    int s = blockIdx.x * 4 + (threadIdx.x >> 6);
    float pmv = pml[(size_t)s * 64 + t];
    float m = pmv;
#pragma unroll
    for (int off = 1; off < 64; off <<= 1) m = fmaxf(m, __shfl_xor(m, off));
    float fc = __expf(SCALE_ * (pmv - m));
    float g = pz[(size_t)s * 64 + t] * fc;
#pragma unroll
    for (int off = 1; off < 64; off <<= 1) g += __shfl_xor(g, off);
    pml[(size_t)s * 64 + t] = fc * (1.0f / g);
}

// ---------------- K6: deconv GEMM (f16), split-K z=2, 2-deep pipelined, fused zr ----------
// A-fragments scaled by facs (f16, LDS-cached, stride-33 padded) right before MFMA:
// per K-step the factor is constant per row (one l-block), so 4 pk-mul per fragment.
// VALU co-issues with MFMA (m114). Staging pipeline/swizzle identical to round-6 proven.
__global__ __launch_bounds__(256) void k_gemm2_mfma(const _Float16* __restrict__ softT,
                                                    const _Float16* __restrict__ colsT,
                                                    const float* __restrict__ facs,
                                                    float* __restrict__ patchP) {
    __shared__ _Float16 AsB[2][16384];   // per buf: A 128x64 (8192) + B 128x64 (8192)
    __shared__ _Float16 facH[128 * 33];  // this block's 128 rows x 32 l-blocks, padded
    int t = threadIdx.x, lane = t & 63, w = t >> 6;
    int wm = w & 1, wn = w >> 1;
    int flat = blockIdx.x + (blockIdx.y << 3) + (blockIdx.z << 8);  // grid (8,32,2) = 512
    int swz = (flat & 7) * 64 + (flat >> 3);  // XCD k -> contiguous 64-block chunk
    int zp = swz >> 8;
    int rem = swz & 255;
    int yp = rem >> 3, xp = rem & 7;
    int M0 = yp * 128, N0 = xp * 128;
    int kbase = zp * 2048;
    f32x4 acc[4][4] = {};

    auto stage = [&](int k0, int bsel) {
        _Float16* Asb = AsB[bsel];
        _Float16* Bsb = Asb + 8192;
#pragma unroll
        for (int rp = 0; rp < 4; ++rp) {
            int chunk = rp * 256 + t;
            int row = chunk >> 3;
            int kc = (chunk & 7) ^ (row & 7);
            async_copy16(softT + ((size_t)(M0 + row) << 12) + k0 + kc * 8, &Asb[chunk * 8]);
        }
#pragma unroll
        for (int rp = 0; rp < 4; ++rp) {
            int chunk = rp * 256 + t;
            int row = chunk >> 3;
            int kc = (chunk & 7) ^ (row & 7);
            async_copy16(colsT + ((size_t)(N0 + row) << 12) + k0 + kc * 8, &Bsb[chunk * 8]);
        }
    };

    stage(kbase, 0);
    // fill facH while tile-0 loads are in flight
#pragma unroll
    for (int it = 0; it < 16; ++it) {
        int task = it * 256 + t;  // 4096: row = task>>5, lb = task&31
        int row = task >> 5, lb = task & 31;
        facH[row * 33 + lb] = (_Float16)facs[((size_t)(M0 + row) << 6) | (zp * 32 + lb)];
    }
    __syncthreads();  // facH visible (also drains tile-0 staging — needed anyway)
    int buf = 0;
    int qc = lane >> 4, mr = lane & 15;
    for (int k0 = kbase; k0 < kbase + 2048; k0 += 64) {
        if (k0 + 64 < kbase + 2048) {
            stage(k0 + 64, buf ^ 1);
            asm volatile("s_waitcnt vmcnt(8)" ::: "memory");  // current tile's 8 landed
        } else {
            asm volatile("s_waitcnt vmcnt(0)" ::: "memory");
        }
        __builtin_amdgcn_s_barrier();
        _Float16* As = AsB[buf];
        _Float16* Bs = As + 8192;
        int lbi = (k0 - kbase) >> 6;
        _Float16 fh[4];
#pragma unroll
        for (int i = 0; i < 4; ++i) fh[i] = facH[(wm * 64 + i * 16 + mr) * 33 + lbi];
#pragma unroll
        for (int kk = 0; kk < 2; ++kk) {
            int c = kk * 4 + qc;
            f16x8 af[4], bfr[4];
#pragma unroll
            for (int i = 0; i < 4; ++i) {
                int rowa = wm * 64 + i * 16 + mr;
                af[i] = *(const f16x8*)&As[rowa * 64 + (c ^ (rowa & 7)) * 8];
#pragma unroll
                for (int u = 0; u < 8; ++u) af[i][u] *= fh[i];
                int rowb = wn * 64 + i * 16 + mr;
                bfr[i] = *(const f16x8*)&Bs[rowb * 64 + (c ^ (rowb & 7)) * 8];
            }
#pragma unroll
            for (int mt = 0; mt < 4; ++mt)
#pragma unroll
                for (int nt = 0; nt < 4; ++nt)
                    acc[mt][nt] = __builtin_amdgcn_mfma_f32_16x16x32_f16(af[mt], bfr[nt], acc[mt][nt], 0, 0, 0);
        }
        __builtin_amdgcn_s_barrier();  // readers done before next iter overwrites buf^1
        buf ^= 1;
    }
    // n-major epilogue: P[n*4096 + m], 16B-aligned float4 per (mt,nt) (r -> m0+0..3)
    float* P = patchP + ((size_t)zp << 22);
    int col = lane & 15, rq = (lane >> 4) * 4;
#pragma unroll
    for (int mt = 0; mt < 4; ++mt) {
        int m0 = M0 + wm * 64 + mt * 16 + rq;
#pragma unroll
        for (int nt = 0; nt < 4; ++nt) {
            int n = N0 + wn * 64 + nt * 16 + col;
            *(f32x4*)&P[(size_t)n * 4096 + m0] = acc[mt][nt];
        }
    }
}

// ---------------- K7: overlap-add gather over both K-partials, n-major patchP -------------
__global__ void k_col2im(const float* __restrict__ patchP, float* __restrict__ outb) {
    int idx = blockIdx.x * 256 + threadIdx.x;  // C*H*W
    if (idx >= C_ * H_ * W_) return;
    int x = idx & 127, y = (idx >> 7) & 127, c = idx >> 14;
    const float* P0 = patchP;
    const float* P1 = patchP + (1u << 22);
    float acc = 0.f;
    int ki0 = (y + 1) & 1, kj0 = (x + 1) & 1;
#pragma unroll
    for (int ki = ki0; ki < 4; ki += 2) {
        int i = (y + 1 - ki) >> 1;
        if (i < 0 || i >= HS) continue;
#pragma unroll
        for (int kj = kj0; kj < 4; kj += 2) {
            int j = (x + 1 - kj) >> 1;
            if (j < 0 || j >= WS) continue;
            size_t off = ((size_t)(c * 16 + ki * 4 + kj) << 12) + i * 64 + j;
            acc += P0[off] + P1[off];
        }
    }
    outb[idx] = acc;
}

extern "C" void kernel_launch(void* const* d_in, const int* in_sizes, int n_in,
                              void* d_out, int out_size, void* d_ws, size_t ws_size,
                              hipStream_t stream) {
    (void)in_sizes; (void)n_in; (void)out_size; (void)ws_size;
    const float* fg = (const float*)d_in[0];
    const float* bg = (const float*)d_in[1];
    const float* mask = (const float*)d_in[2];
    float* out = (float*)d_out;

    // ---- workspace (float offsets) ----
    float* ws = (float*)d_ws;
    float* scores = ws;                                          // strip-only scores
    float* patchP = ws;                                          // alias: 2 x 4,194,304 f
    float* Y = ws + 16777216;                                    // 16,777,216 f
    _Float16* bgcol = (_Float16*)(ws + 33554432);                // 2,359,296 f16
    _Float16* fgcol = (_Float16*)(ws + 34734080);
    _Float16* softT = (_Float16*)(ws + 38273024);                // 16,777,216 f16
    _Float16* colsT = (_Float16*)(ws + 46661632);                // 4,194,304 f16
    float* pml = ws + 48758784;        // 262,144 (becomes facs in-place after k_facs)
    float* pz = ws + 49020928;         // 262,144
    float* denom_inv = ws + 49283072;  // 8,192 (B*L)
    float* maskedf = ws + 49291264;    // 8,192
    float* ssq = ws + 49299456;        // 8,192

    k_sumsq<<<(B_ * HS * WS) / 256, 256, 0, stream>>>(bg, ssq);
    k_patch_stats<<<(B_ * L_) / 256, 256, 0, stream>>>(mask, ssq, denom_inv, maskedf);

    for (int b = 0; b < B_; ++b) {
        const float* bgb = bg + (size_t)b * C_ * H_ * W_;
        const float* fgb = fg + (size_t)b * C_ * H_ * W_;

        k_prep<<<(2 * L_ * K1_ + NCOL * L_) / 256, 256, 0, stream>>>(bgb, fgb, bgcol, fgcol, colsT);

        dim3 g1(32, 32);
        k_gemm1_mfma<<<g1, 256, 0, stream>>>(bgcol, fgcol, denom_inv + b * L_, scores, Y);
        k_pass1_edge<<<2048, 256, 0, stream>>>(scores, Y);

        k_soft3<<<4096, 256, 0, stream>>>(Y, maskedf + b * L_, softT, pml, pz);
        k_facs<<<1024, 256, 0, stream>>>(pml, pz);

        dim3 g5(8, 32, 2);
        k_gemm2_mfma<<<g5, 256, 0, stream>>>(softT, colsT, pml, patchP);
        k_col2im<<<(C_ * H_ * W_) / 256, 256, 0, stream>>>(patchP, out + (size_t)b * C_ * H_ * W_);
    }
}

// Round 13
// 383.192 us; speedup vs baseline: 1.0784x; 1.0100x over previous
//
#include <hip/hip_runtime.h>
#include <hip/hip_bf16.h>

#define B_ 2
#define C_ 64
#define H_ 128
#define W_ 128
#define HS 64
#define WS 64
#define L_ 4096
#define S_ 4096
#define K1_ 576    // C*3*3
#define NCOL 1024  // C*4*4
#define SCALE_ 10.0f

typedef __attribute__((ext_vector_type(8))) short bf16x8;
typedef __attribute__((ext_vector_type(8))) _Float16 f16x8;
typedef __attribute__((ext_vector_type(4))) float f32x4;

// async global->LDS, 16B per lane (wave-uniform LDS base + lane*16).
__device__ __forceinline__ void async_copy16(const void* gsrc, void* ldst) {
    __builtin_amdgcn_global_load_lds(
        (__attribute__((address_space(1))) const void*)gsrc,
        (__attribute__((address_space(3))) void*)ldst, 16, 0, 0);
}

// transposed flat index within a 64x64 grid
__device__ __forceinline__ int TT(int x) { return ((x & 63) << 6) | (x >> 6); }

// generic 3-tap (d2) gather over Y with exact TT boundary semantics
__device__ __forceinline__ float diag3Y(const float* __restrict__ Y, int l, int s) {
    int tl = TT(l), ts = TT(s);
    float acc = 0.f;
#pragma unroll
    for (int d2 = -1; d2 <= 1; ++d2) {
        int p = tl + d2, q = ts + d2;
        if ((unsigned)p < 4096u && (unsigned)q < 4096u)
            acc += Y[((size_t)TT(p) << 12) + TT(q)];
    }
    return acc;
}

// ---------------- K0a: per-pixel channel sum-of-squares of downsampled bg ----------------
__global__ void k_sumsq(const float* __restrict__ bg, float* __restrict__ ssq) {
    int idx = blockIdx.x * 256 + threadIdx.x;  // B*64*64
    if (idx >= B_ * HS * WS) return;
    int pix = idx & 4095, b = idx >> 12;
    int i = pix >> 6, j = pix & 63;
    float ss = 0.f;
    for (int c = 0; c < C_; ++c) {
        float v = bg[((b * C_ + c) * H_ + 2 * i) * W_ + 2 * j];
        ss += v * v;
    }
    ssq[idx] = ss;
}

// ---------------- K0b: per-patch mask flag + 1/denom (3x3 box) ----------------
__global__ void k_patch_stats(const float* __restrict__ mask, const float* __restrict__ ssq,
                              float* __restrict__ denom_inv, float* __restrict__ maskedf) {
    int idx = blockIdx.x * 256 + threadIdx.x;  // B*L
    if (idx >= B_ * L_) return;
    int b = idx >> 12, l = idx & 4095, lh = l >> 6, lw = l & 63;
    float msum = 0.f, ss = 0.f;
    for (int di = -1; di <= 1; ++di)
        for (int dj = -1; dj <= 1; ++dj) {
            int i = lh + di, j = lw + dj;
            if (i >= 0 && i < HS && j >= 0 && j < WS) {
                msum += mask[(b * H_ + 2 * i) * W_ + 2 * j];
                ss += ssq[(b << 12) + (i << 6) + j];
            }
        }
    maskedf[idx] = (msum == 0.0f) ? 1.0f : 0.0f;
    denom_inv[idx] = 1.0f / fmaxf(sqrtf(ss), 0.001f);
}

// ---------------- K0c: fused prep (R7 scalar form; colsT f16) -----------------------------
__global__ void k_prep(const float* __restrict__ bgb, const float* __restrict__ fgb,
                       _Float16* __restrict__ bcol, _Float16* __restrict__ fcol,
                       _Float16* __restrict__ colsT) {
    int idx = blockIdx.x * 256 + threadIdx.x;
    if (idx < 2 * L_ * K1_) {  // im2col part (block-uniform split)
        int which = idx >= L_ * K1_;
        int id = which ? idx - L_ * K1_ : idx;
        const float* src = which ? fgb : bgb;
        _Float16* dst = which ? fcol : bcol;
        int k = id % K1_;
        int l = id / K1_;
        int c = k / 9, r = k - 9 * c;
        int r3 = r / 3;
        int di = r3 - 1, dj = r - 3 * r3 - 1;
        int i = (l >> 6) + di, j = (l & 63) + dj;
        float v = 0.f;
        if (i >= 0 && i < HS && j >= 0 && j < WS) v = src[(c * H_ + 2 * i) * W_ + 2 * j];
        dst[id] = (_Float16)v;
    } else {  // colsT part
        int id = idx - 2 * L_ * K1_;  // NCOL*L, l fastest
        int l = id & 4095, n = id >> 12;
        int kj = n & 3, ki = (n >> 2) & 3, c = n >> 4;
        int y = 2 * (l >> 6) + ki - 1, x = 2 * (l & 63) + kj - 1;
        float v = 0.f;
        if (y >= 0 && y < H_ && x >= 0 && x < W_) v = bgb[(c * H_ + y) * W_ + x];
        colsT[id] = (_Float16)v;
    }
}

// ---------------- K1: scores GEMM (fp16, BK=64, XOR-8 swizzle, 2-deep pipelined) ----------
// Round-13: + XCD-chunked block remap (T1): each XCD owns an 8Mx16N chunk (24 operand
// panels ~3.5MB, fits its private 4MB L2) instead of the default round-robin that
// replicates every A-panel into all 8 L2s. + setprio(1) around the MFMA cluster (T5).
__global__ __launch_bounds__(256) void k_gemm1_mfma(const _Float16* __restrict__ A,
                                                    const _Float16* __restrict__ Bm,
                                                    const float* __restrict__ dinv,
                                                    float* __restrict__ scores,
                                                    float* __restrict__ Y) {
    __shared__ __align__(16) char shraw[128 * 129 * 4];  // 66048B: 2x32KB staging / epi tile
    int t = threadIdx.x, lane = t & 63, w = t >> 6;
    int wm = w & 1, wn = w >> 1;
    // bijective XCD chunk remap: flat&7 -> XCD, chunk grid 4x2 of (8M x 16N)
    int flat = blockIdx.x + (blockIdx.y << 5);  // 0..1023
    int xcd = flat & 7, idx = flat >> 3;        // 128 blocks per XCD
    int mi = idx >> 4, ni = idx & 15;
    int M0 = ((xcd >> 1) * 8 + mi) * 128;
    int N0 = ((xcd & 1) * 16 + ni) * 128;
    f32x4 acc[4][4] = {};

    auto stage = [&](int k0, int offh) {
        _Float16* Asb = (_Float16*)shraw + offh;
        _Float16* Bsb = Asb + 8192;
#pragma unroll
        for (int rp = 0; rp < 4; ++rp) {
            int chunk = rp * 256 + t;  // 1024 chunks of 16B
            int row = chunk >> 3;
            int kc = (chunk & 7) ^ (row & 7);  // permuted global chunk -> swizzled LDS store
            async_copy16(A + (size_t)(M0 + row) * K1_ + k0 + kc * 8, &Asb[chunk * 8]);
        }
#pragma unroll
        for (int rp = 0; rp < 4; ++rp) {
            int chunk = rp * 256 + t;
            int row = chunk >> 3;
            int kc = (chunk & 7) ^ (row & 7);
            async_copy16(Bm + (size_t)(N0 + row) * K1_ + k0 + kc * 8, &Bsb[chunk * 8]);
        }
    };

    stage(0, 0);
    int buf = 0;
    for (int k0 = 0; k0 < K1_; k0 += 64) {
        if (k0 + 64 < K1_) {
            stage(k0 + 64, (buf ^ 1) * 16384);
            asm volatile("s_waitcnt vmcnt(8)" ::: "memory");  // current tile landed
        } else {
            asm volatile("s_waitcnt vmcnt(0)" ::: "memory");
        }
        __builtin_amdgcn_s_barrier();
        _Float16* As = (_Float16*)shraw + buf * 16384;
        _Float16* Bs = As + 8192;
        int qc = lane >> 4, mr = lane & 15;
#pragma unroll
        for (int kk = 0; kk < 2; ++kk) {
            int c = kk * 4 + qc;
            f16x8 af[4], bfr[4];
#pragma unroll
            for (int i = 0; i < 4; ++i) {
                int ra = wm * 64 + i * 16 + mr;
                int rb = wn * 64 + i * 16 + mr;
                af[i] = *(const f16x8*)&As[ra * 64 + (c ^ (ra & 7)) * 8];
                bfr[i] = *(const f16x8*)&Bs[rb * 64 + (c ^ (rb & 7)) * 8];
            }
            __builtin_amdgcn_s_setprio(1);
#pragma unroll
            for (int mt = 0; mt < 4; ++mt)
#pragma unroll
                for (int nt = 0; nt < 4; ++nt)
                    acc[mt][nt] = __builtin_amdgcn_mfma_f32_16x16x32_f16(af[mt], bfr[nt], acc[mt][nt], 0, 0, 0);
            __builtin_amdgcn_s_setprio(0);
        }
        __builtin_amdgcn_s_barrier();  // readers done before next iter overwrites buf^1
        buf ^= 1;
    }
    int col = lane & 15, rq = (lane >> 4) * 4;
    // strip writes: raw scores on rows/cols {0,1,126,127} of this tile
#pragma unroll
    for (int mt = 0; mt < 4; ++mt)
#pragma unroll
        for (int r = 0; r < 4; ++r) {
            int ml = wm * 64 + mt * 16 + rq + r;
            bool rstrip = (ml <= 1) || (ml >= 126);
            float dv = dinv[M0 + ml];
#pragma unroll
            for (int nt = 0; nt < 4; ++nt) {
                int nl = wn * 64 + nt * 16 + col;
                bool cstrip = (nl <= 1) || (nl >= 126);
                if (rstrip || cstrip)
                    scores[((size_t)(M0 + ml) << 12) + N0 + nl] = acc[mt][nt][r] * dv;
            }
        }
    // Y interior via single full-tile LDS pass (128x129 f32)
    float* sm = (float*)shraw;
#pragma unroll
    for (int mt = 0; mt < 4; ++mt)
#pragma unroll
        for (int r = 0; r < 4; ++r) {
            int ml = wm * 64 + mt * 16 + rq + r;
            float dv = dinv[M0 + ml];
#pragma unroll
            for (int nt = 0; nt < 4; ++nt) {
                int nl = wn * 64 + nt * 16 + col;
                sm[ml * 129 + nl] = acc[mt][nt][r] * dv;
            }
        }
    __syncthreads();
    for (int e = t; e < 126 * 128; e += 256) {
        int rr = 1 + (e >> 7);
        int cc = e & 127;
        if (cc < 1 || cc > 126) continue;
        float y = sm[(rr - 1) * 129 + cc - 1] + sm[rr * 129 + cc] + sm[(rr + 1) * 129 + cc + 1];
        Y[((size_t)(M0 + rr) << 12) + N0 + cc] = y;
    }
}

// ---------------- K2a: Y boundary rows/cols from score strips (exact flat bounds) ---------
__global__ void k_pass1_edge(const float* __restrict__ scores, float* __restrict__ Y) {
    int idx = blockIdx.x * 256 + threadIdx.x;  // 2*64*4096
    int a, c;
    if (idx < 262144) {
        int ri = idx >> 12;  // 0..63
        a = (ri >> 1) * 128 + ((ri & 1) ? 127 : 0);
        c = idx & 4095;
    } else {
        int j = idx - 262144;
        int ci = j >> 12;
        c = (ci >> 1) * 128 + ((ci & 1) ? 127 : 0);
        a = j & 4095;
    }
    float acc = 0.f;
#pragma unroll
    for (int d = -1; d <= 1; ++d) {
        int aa = a + d, cc = c + d;
        if ((unsigned)aa < 4096u && (unsigned)cc < 4096u)
            acc += scores[((size_t)aa << 12) + cc];
    }
    Y[((size_t)a << 12) + c] = acc;
}

// ---------------- K2b: pass2 — 3-tap + local-max exp + transpose -> softT (f16) -----------
__global__ __launch_bounds__(256) void k_soft3(const float* __restrict__ Y,
                                               const float* __restrict__ maskedf,
                                               _Float16* __restrict__ softT,
                                               float* __restrict__ pml, float* __restrict__ pz) {
    __shared__ float tile[64][65];
    __shared__ float red[16][64];
    __shared__ float mloc[64];
    int t = threadIdx.x;
    int sx4 = t & 15, lg = t >> 4;
    int bid = blockIdx.x;
    int swz = (bid & 7) * 512 + (bid >> 3);
    int dg = swz >> 6, pos = swz & 63;
    int by = pos, bx = (pos + dg) & 63;
    int s0 = bx * 64, l0 = by * 64;
    bool interior = (bx >= 1) && (bx <= 62) && (by >= 1) && (by <= 62);
    float p0 = -3.0e38f, p1 = -3.0e38f, p2 = -3.0e38f, p3 = -3.0e38f;
    if (interior) {
        float4 v[12];
        float mk[4];
#pragma unroll
        for (int j = 0; j < 4; ++j) {
            int lloc = lg + 16 * j;
#pragma unroll
            for (int d2 = 0; d2 < 3; ++d2) {
                const float* p = Y + ((size_t)(64 * (by + d2 - 1) + lloc) << 12) + 64 * (bx + d2 - 1) + 4 * sx4;
                v[j * 3 + d2] = *(const float4*)p;
            }
        }
#pragma unroll
        for (int j = 0; j < 4; ++j) mk[j] = maskedf[l0 + lg + 16 * j];
#pragma unroll
        for (int j = 0; j < 4; ++j) {
            int lloc = lg + 16 * j;
            float a0 = v[j * 3].x + v[j * 3 + 1].x + v[j * 3 + 2].x;
            float a1 = v[j * 3].y + v[j * 3 + 1].y + v[j * 3 + 2].y;
            float a2 = v[j * 3].z + v[j * 3 + 1].z + v[j * 3 + 2].z;
            float a3 = v[j * 3].w + v[j * 3 + 1].w + v[j * 3 + 2].w;
            if (mk[j] != 0.f) { a0 = -1000.f; a1 = -1000.f; a2 = -1000.f; a3 = -1000.f; }
            tile[lloc][4 * sx4 + 0] = a0;
            tile[lloc][4 * sx4 + 1] = a1;
            tile[lloc][4 * sx4 + 2] = a2;
            tile[lloc][4 * sx4 + 3] = a3;
            p0 = fmaxf(p0, a0); p1 = fmaxf(p1, a1); p2 = fmaxf(p2, a2); p3 = fmaxf(p3, a3);
        }
    } else {
#pragma unroll
        for (int j = 0; j < 4; ++j) {
            int lloc = lg + 16 * j;
            int l = l0 + lloc;
            bool mk = (maskedf[l] != 0.f);
            float a0 = mk ? -1000.f : diag3Y(Y, l, s0 + 4 * sx4 + 0);
            float a1 = mk ? -1000.f : diag3Y(Y, l, s0 + 4 * sx4 + 1);
            float a2 = mk ? -1000.f : diag3Y(Y, l, s0 + 4 * sx4 + 2);
            float a3 = mk ? -1000.f : diag3Y(Y, l, s0 + 4 * sx4 + 3);
            tile[lloc][4 * sx4 + 0] = a0;
            tile[lloc][4 * sx4 + 1] = a1;
            tile[lloc][4 * sx4 + 2] = a2;
            tile[lloc][4 * sx4 + 3] = a3;
            p0 = fmaxf(p0, a0); p1 = fmaxf(p1, a1); p2 = fmaxf(p2, a2); p3 = fmaxf(p3, a3);
        }
    }
    red[lg][4 * sx4 + 0] = p0;
    red[lg][4 * sx4 + 1] = p1;
    red[lg][4 * sx4 + 2] = p2;
    red[lg][4 * sx4 + 3] = p3;
    __syncthreads();
    if (t < 64) {
        float m = -3.0e38f;
#pragma unroll
        for (int g = 0; g < 16; ++g) m = fmaxf(m, red[g][t]);
        mloc[t] = m;
        pml[(size_t)(s0 + t) * 64 + by] = m;
    }
    __syncthreads();
    float m0 = mloc[4 * sx4 + 0], m1 = mloc[4 * sx4 + 1], m2 = mloc[4 * sx4 + 2], m3 = mloc[4 * sx4 + 3];
    float z0 = 0.f, z1 = 0.f, z2 = 0.f, z3 = 0.f;
#pragma unroll
    for (int j = 0; j < 4; ++j) {
        int lloc = lg + 16 * j;
        float e0 = __expf(SCALE_ * (tile[lloc][4 * sx4 + 0] - m0));
        float e1 = __expf(SCALE_ * (tile[lloc][4 * sx4 + 1] - m1));
        float e2 = __expf(SCALE_ * (tile[lloc][4 * sx4 + 2] - m2));
        float e3 = __expf(SCALE_ * (tile[lloc][4 * sx4 + 3] - m3));
        tile[lloc][4 * sx4 + 0] = e0;
        tile[lloc][4 * sx4 + 1] = e1;
        tile[lloc][4 * sx4 + 2] = e2;
        tile[lloc][4 * sx4 + 3] = e3;
        z0 += e0; z1 += e1; z2 += e2; z3 += e3;
    }
    red[lg][4 * sx4 + 0] = z0;
    red[lg][4 * sx4 + 1] = z1;
    red[lg][4 * sx4 + 2] = z2;
    red[lg][4 * sx4 + 3] = z3;
    __syncthreads();
    if (t < 64) {
        float zz = 0.f;
#pragma unroll
        for (int g = 0; g < 16; ++g) zz += red[g][t];
        pz[(size_t)(s0 + t) * 64 + by] = zz;
    }
#pragma unroll
    for (int pp = 0; pp < 2; ++pp) {
        int chunk = pp * 256 + t;
        int sloc = chunk >> 3, lb = (chunk & 7) * 8;
        f16x8 o;
#pragma unroll
        for (int k = 0; k < 8; ++k) o[k] = (_Float16)tile[lb + k][sloc];
        *(f16x8*)(softT + ((size_t)(s0 + sloc) << 12) + l0 + lb) = o;
    }
}

// ---------------- K3: facs = fc/g computed IN-PLACE into pml (replaces k_zr) --------------
__global__ __launch_bounds__(256) void k_facs(float* __restrict__ pml,
                                              const float* __restrict__ pz) {
    int t = threadIdx.x & 63;
    int s = blockIdx.x * 4 + (threadIdx.x >> 6);
    float pmv = pml[(size_t)s * 64 + t];
    float m = pmv;
#pragma unroll
    for (int off = 1; off < 64; off <<= 1) m = fmaxf(m, __shfl_xor(m, off));
    float fc = __expf(SCALE_ * (pmv - m));
    float g = pz[(size_t)s * 64 + t] * fc;
#pragma unroll
    for (int off = 1; off < 64; off <<= 1) g += __shfl_xor(g, off);
    pml[(size_t)s * 64 + t] = fc * (1.0f / g);
}

// ---------------- K6: deconv GEMM (f16), split-K z=2, 2-deep pipelined, fused zr ----------
// A-fragments scaled by facs (f16, LDS-cached, stride-33 padded) right before MFMA;
// + setprio around MFMA cluster (T5).
__global__ __launch_bounds__(256) void k_gemm2_mfma(const _Float16* __restrict__ softT,
                                                    const _Float16* __restrict__ colsT,
                                                    const float* __restrict__ facs,
                                                    float* __restrict__ patchP) {
    __shared__ _Float16 AsB[2][16384];   // per buf: A 128x64 (8192) + B 128x64 (8192)
    __shared__ _Float16 facH[128 * 33];  // this block's 128 rows x 32 l-blocks, padded
    int t = threadIdx.x, lane = t & 63, w = t >> 6;
    int wm = w & 1, wn = w >> 1;
    int flat = blockIdx.x + (blockIdx.y << 3) + (blockIdx.z << 8);  // grid (8,32,2) = 512
    int swz = (flat & 7) * 64 + (flat >> 3);  // XCD k -> contiguous 64-block chunk
    int zp = swz >> 8;
    int rem = swz & 255;
    int yp = rem >> 3, xp = rem & 7;
    int M0 = yp * 128, N0 = xp * 128;
    int kbase = zp * 2048;
    f32x4 acc[4][4] = {};

    auto stage = [&](int k0, int bsel) {
        _Float16* Asb = AsB[bsel];
        _Float16* Bsb = Asb + 8192;
#pragma unroll
        for (int rp = 0; rp < 4; ++rp) {
            int chunk = rp * 256 + t;
            int row = chunk >> 3;
            int kc = (chunk & 7) ^ (row & 7);
            async_copy16(softT + ((size_t)(M0 + row) << 12) + k0 + kc * 8, &Asb[chunk * 8]);
        }
#pragma unroll
        for (int rp = 0; rp < 4; ++rp) {
            int chunk = rp * 256 + t;
            int row = chunk >> 3;
            int kc = (chunk & 7) ^ (row & 7);
            async_copy16(colsT + ((size_t)(N0 + row) << 12) + k0 + kc * 8, &Bsb[chunk * 8]);
        }
    };

    stage(kbase, 0);
    // fill facH while tile-0 loads are in flight
#pragma unroll
    for (int it = 0; it < 16; ++it) {
        int task = it * 256 + t;  // 4096: row = task>>5, lb = task&31
        int row = task >> 5, lb = task & 31;
        facH[row * 33 + lb] = (_Float16)facs[((size_t)(M0 + row) << 6) | (zp * 32 + lb)];
    }
    __syncthreads();  // facH visible (also drains tile-0 staging — needed anyway)
    int buf = 0;
    int qc = lane >> 4, mr = lane & 15;
    for (int k0 = kbase; k0 < kbase + 2048; k0 += 64) {
        if (k0 + 64 < kbase + 2048) {
            stage(k0 + 64, buf ^ 1);
            asm volatile("s_waitcnt vmcnt(8)" ::: "memory");  // current tile's 8 landed
        } else {
            asm volatile("s_waitcnt vmcnt(0)" ::: "memory");
        }
        __builtin_amdgcn_s_barrier();
        _Float16* As = AsB[buf];
        _Float16* Bs = As + 8192;
        int lbi = (k0 - kbase) >> 6;
        _Float16 fh[4];
#pragma unroll
        for (int i = 0; i < 4; ++i) fh[i] = facH[(wm * 64 + i * 16 + mr) * 33 + lbi];
#pragma unroll
        for (int kk = 0; kk < 2; ++kk) {
            int c = kk * 4 + qc;
            f16x8 af[4], bfr[4];
#pragma unroll
            for (int i = 0; i < 4; ++i) {
                int rowa = wm * 64 + i * 16 + mr;
                af[i] = *(const f16x8*)&As[rowa * 64 + (c ^ (rowa & 7)) * 8];
#pragma unroll
                for (int u = 0; u < 8; ++u) af[i][u] *= fh[i];
                int rowb = wn * 64 + i * 16 + mr;
                bfr[i] = *(const f16x8*)&Bs[rowb * 64 + (c ^ (rowb & 7)) * 8];
            }
            __builtin_amdgcn_s_setprio(1);
#pragma unroll
            for (int mt = 0; mt < 4; ++mt)
#pragma unroll
                for (int nt = 0; nt < 4; ++nt)
                    acc[mt][nt] = __builtin_amdgcn_mfma_f32_16x16x32_f16(af[mt], bfr[nt], acc[mt][nt], 0, 0, 0);
            __builtin_amdgcn_s_setprio(0);
        }
        __builtin_amdgcn_s_barrier();  // readers done before next iter overwrites buf^1
        buf ^= 1;
    }
    // n-major epilogue: P[n*4096 + m], 16B-aligned float4 per (mt,nt) (r -> m0+0..3)
    float* P = patchP + ((size_t)zp << 22);
    int col = lane & 15, rq = (lane >> 4) * 4;
#pragma unroll
    for (int mt = 0; mt < 4; ++mt) {
        int m0 = M0 + wm * 64 + mt * 16 + rq;
#pragma unroll
        for (int nt = 0; nt < 4; ++nt) {
            int n = N0 + wn * 64 + nt * 16 + col;
            *(f32x4*)&P[(size_t)n * 4096 + m0] = acc[mt][nt];
        }
    }
}

// ---------------- K7: overlap-add gather over both K-partials, n-major patchP -------------
__global__ void k_col2im(const float* __restrict__ patchP, float* __restrict__ outb) {
    int idx = blockIdx.x * 256 + threadIdx.x;  // C*H*W
    if (idx >= C_ * H_ * W_) return;
    int x = idx & 127, y = (idx >> 7) & 127, c = idx >> 14;
    const float* P0 = patchP;
    const float* P1 = patchP + (1u << 22);
    float acc = 0.f;
    int ki0 = (y + 1) & 1, kj0 = (x + 1) & 1;
#pragma unroll
    for (int ki = ki0; ki < 4; ki += 2) {
        int i = (y + 1 - ki) >> 1;
        if (i < 0 || i >= HS) continue;
#pragma unroll
        for (int kj = kj0; kj < 4; kj += 2) {
            int j = (x + 1 - kj) >> 1;
            if (j < 0 || j >= WS) continue;
            size_t off = ((size_t)(c * 16 + ki * 4 + kj) << 12) + i * 64 + j;
            acc += P0[off] + P1[off];
        }
    }
    outb[idx] = acc;
}

extern "C" void kernel_launch(void* const* d_in, const int* in_sizes, int n_in,
                              void* d_out, int out_size, void* d_ws, size_t ws_size,
                              hipStream_t stream) {
    (void)in_sizes; (void)n_in; (void)out_size; (void)ws_size;
    const float* fg = (const float*)d_in[0];
    const float* bg = (const float*)d_in[1];
    const float* mask = (const float*)d_in[2];
    float* out = (float*)d_out;

    // ---- workspace (float offsets) ----
    float* ws = (float*)d_ws;
    float* scores = ws;                                          // strip-only scores
    float* patchP = ws;                                          // alias: 2 x 4,194,304 f
    float* Y = ws + 16777216;                                    // 16,777,216 f
    _Float16* bgcol = (_Float16*)(ws + 33554432);                // 2,359,296 f16
    _Float16* fgcol = (_Float16*)(ws + 34734080);
    _Float16* softT = (_Float16*)(ws + 38273024);                // 16,777,216 f16
    _Float16* colsT = (_Float16*)(ws + 46661632);                // 4,194,304 f16
    float* pml = ws + 48758784;        // 262,144 (becomes facs in-place after k_facs)
    float* pz = ws + 49020928;         // 262,144
    float* denom_inv = ws + 49283072;  // 8,192 (B*L)
    float* maskedf = ws + 49291264;    // 8,192
    float* ssq = ws + 49299456;        // 8,192

    k_sumsq<<<(B_ * HS * WS) / 256, 256, 0, stream>>>(bg, ssq);
    k_patch_stats<<<(B_ * L_) / 256, 256, 0, stream>>>(mask, ssq, denom_inv, maskedf);

    for (int b = 0; b < B_; ++b) {
        const float* bgb = bg + (size_t)b * C_ * H_ * W_;
        const float* fgb = fg + (size_t)b * C_ * H_ * W_;

        k_prep<<<(2 * L_ * K1_ + NCOL * L_) / 256, 256, 0, stream>>>(bgb, fgb, bgcol, fgcol, colsT);

        dim3 g1(32, 32);
        k_gemm1_mfma<<<g1, 256, 0, stream>>>(bgcol, fgcol, denom_inv + b * L_, scores, Y);
        k_pass1_edge<<<2048, 256, 0, stream>>>(scores, Y);

        k_soft3<<<4096, 256, 0, stream>>>(Y, maskedf + b * L_, softT, pml, pz);
        k_facs<<<1024, 256, 0, stream>>>(pml, pz);

        dim3 g5(8, 32, 2);
        k_gemm2_mfma<<<g5, 256, 0, stream>>>(softT, colsT, pml, patchP);
        k_col2im<<<(C_ * H_ * W_) / 256, 256, 0, stream>>>(patchP, out + (size_t)b * C_ * H_ * W_);
    }
}